// Round 1
// baseline (501.697 us; speedup 1.0000x reference)
//
#include <hip/hip_runtime.h>

// ---------------------------------------------------------------------------
// AttentionCritic on MI355X — round 1: bf16 MFMA pipeline, correctness-first.
// N=8 agents, B=8192, S=64, A=16, H=512, E=4 heads, D=128.
// ---------------------------------------------------------------------------

#define DEVI __device__ __forceinline__

typedef unsigned short us16;
typedef __bf16 bf16x8 __attribute__((ext_vector_type(8)));
typedef float f32x4 __attribute__((ext_vector_type(4)));
typedef unsigned short u16x8 __attribute__((ext_vector_type(8)));

DEVI us16 f2bf(float f) {
  unsigned u = __builtin_bit_cast(unsigned, f);
  u += 0x7FFFu + ((u >> 16) & 1u);          // round-to-nearest-even
  return (us16)(u >> 16);
}
DEVI float bf2f(us16 h) {
  unsigned u = ((unsigned)h) << 16;
  return __builtin_bit_cast(float, u);
}
DEVI float lrelu(float v) { return v > 0.f ? v : 0.01f * v; }
DEVI int pk2(float a, float b) { return (int)f2bf(a) | ((int)f2bf(b) << 16); }

// ---------------------------------------------------------------------------
// Transpose + fp32->bf16 convert:  dst[s][dstRowOff+o][k] = src[s][k][o] (k<K else 0)
// block (32,8), grid (Kpad/32, ceil(O/32), slices)
// ---------------------------------------------------------------------------
__global__ void tconv_k(const float* __restrict__ src, long srcSlice, int K, int O,
                        us16* __restrict__ dst, long dstSlice, int dstRowOff,
                        int ldd, int Kpad)
{
  __shared__ float t[32][33];
  const int s = blockIdx.z;
  const int k0 = blockIdx.x * 32, o0 = blockIdx.y * 32;
  const int lx = threadIdx.x, ly = threadIdx.y;
#pragma unroll
  for (int i = 0; i < 4; i++) {
    int k = k0 + ly + i * 8, o = o0 + lx;
    float v = 0.f;
    if (k < K && o < O) v = src[(long)s * srcSlice + (long)k * O + o];
    t[ly + i * 8][lx] = v;
  }
  __syncthreads();
#pragma unroll
  for (int i = 0; i < 4; i++) {
    int o = o0 + ly + i * 8, k = k0 + lx;
    if (o < O && k < Kpad)
      dst[(long)s * dstSlice + (long)(dstRowOff + o) * ldd + k] = f2bf(t[lx][ly + i * 8]);
  }
}

// ---------------------------------------------------------------------------
// Generic MFMA GEMM: C[M=8192 x N] = A[M x K] * Bt[N x K]^T (+bias, lrelu, ...)
// 128x128 tile, 256 threads = 4 waves (2x2 of 64x64), BK=32, single-buffer LDS.
// ---------------------------------------------------------------------------
enum { ASRC_BF16 = 0, ASRC_BF16_CAT = 1, ASRC_F32 = 2, ASRC_F32_CAT = 3 };
enum { EPI_STORE = 0, EPI_KSV = 1, EPI_DOT = 2 };

template <int ASRC, int EPI, int KTOT>
__global__ __launch_bounds__(256, 2)
void gemm_k(const void* __restrict__ Ap, long aSlice,
            const void* __restrict__ A2p, long a2Slice,
            const us16* __restrict__ Btp, long bSlice,
            const float* __restrict__ bias, long biasSlice,
            us16* __restrict__ outB, long outSlice, long outRow,
            const float* __restrict__ dotW, float* __restrict__ partial)
{
  __shared__ us16 lA[128 * 40];   // padded stride 40 -> 2-way max bank conflicts
  __shared__ us16 lB[128 * 40];
  const int tid = threadIdx.x;
  const int z = blockIdx.z;
  const int m0 = blockIdx.x * 128;
  const int n0 = blockIdx.y * 128;
  const int srow = tid >> 1;            // staging row 0..127
  const int scol0 = (tid & 1) * 16;     // staging col 0 or 16
  const int wv = tid >> 6, lane = tid & 63;
  const int wm = (wv >> 1) * 64, wn = (wv & 1) * 64;
  const int fr = lane & 15, fk = (lane >> 4) * 8;
  const int rbase = (lane >> 4) * 4;

  f32x4 acc[4][4];
#pragma unroll
  for (int i = 0; i < 4; i++)
#pragma unroll
    for (int j = 0; j < 4; j++) acc[i][j] = f32x4{0.f, 0.f, 0.f, 0.f};

  const us16* bgl = Btp + (long)z * bSlice + (long)(n0 + srow) * KTOT + scol0;

  for (int k0 = 0; k0 < KTOT; k0 += 32) {
    int4 ra0, ra1, rb0, rb1;
    { const int4* bp = (const int4*)(bgl + k0); rb0 = bp[0]; rb1 = bp[1]; }
    if constexpr (ASRC == ASRC_BF16) {
      const us16* a = (const us16*)Ap + (long)z * aSlice + (long)(m0 + srow) * KTOT + (k0 + scol0);
      ra0 = ((const int4*)a)[0]; ra1 = ((const int4*)a)[1];
    } else if constexpr (ASRC == ASRC_BF16_CAT) {
      int kg = k0 + scol0;  // chunk pair [kg,kg+16) never straddles 512
      const us16* a;
      if (kg < 512) a = (const us16*)Ap + (long)z * aSlice + (long)(m0 + srow) * 512 + kg;
      else          a = (const us16*)A2p + (long)z * a2Slice + (long)(m0 + srow) * 512 + (kg - 512);
      ra0 = ((const int4*)a)[0]; ra1 = ((const int4*)a)[1];
    } else {
      int kg = k0 + scol0;
      const float* a = nullptr;
      if constexpr (ASRC == ASRC_F32) {
        a = (const float*)Ap + (long)z * aSlice + (long)(m0 + srow) * 64 + kg;
      } else {  // states(0..63) | actions(64..79) | zero pad(80..95); 16-chunks never straddle
        if (kg < 64)      a = (const float*)Ap + (long)z * aSlice + (long)(m0 + srow) * 64 + kg;
        else if (kg < 80) a = (const float*)A2p + (long)z * a2Slice + (long)(m0 + srow) * 16 + (kg - 64);
      }
      float4 f0, f1, f2, f3;
      if (a) { const float4* ap = (const float4*)a; f0 = ap[0]; f1 = ap[1]; f2 = ap[2]; f3 = ap[3]; }
      else   { f0 = make_float4(0.f, 0.f, 0.f, 0.f); f1 = f0; f2 = f0; f3 = f0; }
      ra0.x = pk2(f0.x, f0.y); ra0.y = pk2(f0.z, f0.w); ra0.z = pk2(f1.x, f1.y); ra0.w = pk2(f1.z, f1.w);
      ra1.x = pk2(f2.x, f2.y); ra1.y = pk2(f2.z, f2.w); ra1.z = pk2(f3.x, f3.y); ra1.w = pk2(f3.z, f3.w);
    }
    __syncthreads();
    *(int4*)&lA[srow * 40 + scol0]     = ra0;
    *(int4*)&lA[srow * 40 + scol0 + 8] = ra1;
    *(int4*)&lB[srow * 40 + scol0]     = rb0;
    *(int4*)&lB[srow * 40 + scol0 + 8] = rb1;
    __syncthreads();
    bf16x8 af[4], bf[4];
#pragma unroll
    for (int f = 0; f < 4; f++) af[f] = *(const bf16x8*)&lA[(wm + f * 16 + fr) * 40 + fk];
#pragma unroll
    for (int f = 0; f < 4; f++) bf[f] = *(const bf16x8*)&lB[(wn + f * 16 + fr) * 40 + fk];
#pragma unroll
    for (int fm = 0; fm < 4; fm++)
#pragma unroll
      for (int fn = 0; fn < 4; fn++)
        acc[fm][fn] = __builtin_amdgcn_mfma_f32_16x16x32_bf16(af[fm], bf[fn], acc[fm][fn], 0, 0, 0);
  }

  if constexpr (EPI == EPI_DOT) {
    // hidden = lrelu(acc + bc1[col]); partial[row] += hidden * W2[col]; per-block slot store
    const float* bsl = bias + (long)z * 512;
    const float* wsl = dotW + (long)z * 512;
#pragma unroll
    for (int fm = 0; fm < 4; fm++) {
#pragma unroll
      for (int j = 0; j < 4; j++) {
        float p = 0.f;
#pragma unroll
        for (int fn = 0; fn < 4; fn++) {
          int col = n0 + wn + fn * 16 + fr;
          float v = acc[fm][fn][j] + bsl[col];
          v = lrelu(v);
          p += v * wsl[col];
        }
        p += __shfl_xor(p, 1); p += __shfl_xor(p, 2); p += __shfl_xor(p, 4); p += __shfl_xor(p, 8);
        if (fr == 0) {
          long row = (long)z * 8192 + (m0 + wm + fm * 16 + rbase + j);
          partial[row * 8 + blockIdx.y * 2 + (wv & 1)] = p;
        }
      }
    }
  } else {
#pragma unroll
    for (int fm = 0; fm < 4; fm++) {
#pragma unroll
      for (int fn = 0; fn < 4; fn++) {
        int col = n0 + wn + fn * 16 + fr;
        float badd = 0.f; bool act = false;
        if constexpr (EPI == EPI_STORE) { badd = bias[(long)z * biasSlice + col]; act = true; }
        else { if (col >= 256) { badd = bias[col - 256]; act = true; } }  // vals third only
        us16* op = outB + (long)z * outSlice + (long)(m0 + wm + fm * 16 + rbase) * outRow + col;
#pragma unroll
        for (int j = 0; j < 4; j++) {
          float v = acc[fm][fn][j] + badd;
          if (act) v = lrelu(v);
          op[(long)j * outRow] = f2bf(v);
        }
      }
    }
  }
}

// ---------------------------------------------------------------------------
// Attention: per (b,e): logits = sel_i . key_j / sqrt(128); softmax_j; PV.
// KSV layout [b][n][384] (cols: 0-127 key, 128-255 sel, 256-383 val).
// One wave per b; 4 waves/block; LDS rows padded to 392 (conflict-free dots).
// ---------------------------------------------------------------------------
__global__ __launch_bounds__(256, 2)
void attn_k(const us16* __restrict__ ksv, us16* __restrict__ other, int e)
{
  __shared__ us16 t[4][8 * 392];
  const int wv = threadIdx.x >> 6, lane = threadIdx.x & 63;
  const long b = (long)blockIdx.x * 4 + wv;
  const us16* src = ksv + b * 3072;
#pragma unroll
  for (int i = 0; i < 6; i++) {
    int c = i * 64 + lane;                 // 384 16B-chunks (8 rows x 48)
    int r = c / 48, cc = c - r * 48;
    *(int4*)&t[wv][r * 392 + cc * 8] = *(const int4*)&src[c * 8];
  }
  __syncthreads();
  const int i = lane >> 3, j = lane & 7;   // lane = i*8 + j
  const us16* selp = &t[wv][i * 392 + 128];
  const us16* keyp = &t[wv][j * 392];
  float acc = 0.f;
#pragma unroll
  for (int d = 0; d < 128; d += 8) {
    u16x8 s8 = *(const u16x8*)&selp[d];
    u16x8 k8 = *(const u16x8*)&keyp[d];
#pragma unroll
    for (int q = 0; q < 8; q++) acc += bf2f(s8[q]) * bf2f(k8[q]);
  }
  acc *= 0.088388347648318447f;            // 1/sqrt(128)
  float mx = acc;
  mx = fmaxf(mx, __shfl_xor(mx, 1)); mx = fmaxf(mx, __shfl_xor(mx, 2)); mx = fmaxf(mx, __shfl_xor(mx, 4));
  float ex = __expf(acc - mx);
  float sm = ex;
  sm += __shfl_xor(sm, 1); sm += __shfl_xor(sm, 2); sm += __shfl_xor(sm, 4);
  float wsm = ex / sm;
  float wj[8];
  const int ibase = lane & 56;
#pragma unroll
  for (int jj = 0; jj < 8; jj++) wj[jj] = __shfl(wsm, ibase + jj);
  const int dbase = (lane & 7) * 16;       // this lane: agent i, dims dbase..dbase+15
  float o[16];
#pragma unroll
  for (int q = 0; q < 16; q++) o[q] = 0.f;
#pragma unroll
  for (int jj = 0; jj < 8; jj++) {
    u16x8 v0 = *(const u16x8*)&t[wv][jj * 392 + 256 + dbase];
    u16x8 v1 = *(const u16x8*)&t[wv][jj * 392 + 256 + dbase + 8];
    float wgt = wj[jj];
#pragma unroll
    for (int q = 0; q < 8; q++) { o[q] += wgt * bf2f(v0[q]); o[8 + q] += wgt * bf2f(v1[q]); }
  }
  u16x8 r0, r1;
#pragma unroll
  for (int q = 0; q < 8; q++) { r0[q] = f2bf(o[q]); r1[q] = f2bf(o[8 + q]); }
  us16* dst = other + ((long)i * 8192 + b) * 512 + e * 128 + dbase;
  *(u16x8*)&dst[0] = r0;
  *(u16x8*)&dst[8] = r1;
}

// q[r] = b2[r>>13] + sum of 8 per-block partials
__global__ void reduce_dot_k(const float* __restrict__ part, const float* __restrict__ b2,
                             float* __restrict__ out)
{
  int r = blockIdx.x * 256 + threadIdx.x;  // 0..65535
  const float4* p = (const float4*)(part + (long)r * 8);
  float4 a = p[0], b = p[1];
  out[r] = b2[r >> 13] + ((a.x + a.y) + (a.z + a.w)) + ((b.x + b.y) + (b.z + b.w));
}

// ---------------------------------------------------------------------------
extern "C" void kernel_launch(void* const* d_in, const int* in_sizes, int n_in,
                              void* d_out, int out_size, void* d_ws, size_t ws_size,
                              hipStream_t stream)
{
  const float* states = (const float*)d_in[0];
  const float* actions= (const float*)d_in[1];
  const float* Ws  = (const float*)d_in[2];
  const float* bs  = (const float*)d_in[3];
  const float* Wsa = (const float*)d_in[4];
  const float* bsa = (const float*)d_in[5];
  const float* Wk  = (const float*)d_in[6];
  const float* Wsel= (const float*)d_in[7];
  const float* Wv  = (const float*)d_in[8];
  const float* bv  = (const float*)d_in[9];
  const float* Wc1 = (const float*)d_in[10];
  const float* bc1 = (const float*)d_in[11];
  const float* Wc2 = (const float*)d_in[12];
  const float* bc2 = (const float*)d_in[13];
  const float* Wv1 = (const float*)d_in[14];
  const float* bv1 = (const float*)d_in[15];
  const float* Wv2 = (const float*)d_in[16];
  const float* bv2 = (const float*)d_in[17];

  char* ws = (char*)d_ws;
  constexpr size_t OFF_WST   = 0;
  constexpr size_t OFF_WSAT  = OFF_WST   + (size_t)8 * 512 * 64 * 2;
  constexpr size_t OFF_WKVST = OFF_WSAT  + (size_t)8 * 512 * 96 * 2;
  constexpr size_t OFF_WC1T  = OFF_WKVST + (size_t)4 * 384 * 512 * 2;
  constexpr size_t OFF_WV1T  = OFF_WC1T  + (size_t)8 * 512 * 1024 * 2;
  constexpr size_t OFF_ENC   = OFF_WV1T  + (size_t)8 * 512 * 1024 * 2;
  constexpr size_t OFF_OTHER = OFF_ENC   + (size_t)8 * 8192 * 512 * 2;
  constexpr size_t OFF_KSV   = OFF_OTHER + (size_t)8 * 8192 * 512 * 2;
  constexpr size_t OFF_PART  = OFF_KSV   + (size_t)8192 * 8 * 384 * 2;
  constexpr size_t NEED      = OFF_PART  + (size_t)65536 * 8 * 4;
  if (ws_size < NEED) return;  // workspace too small -> loud validation failure

  us16* WST   = (us16*)(ws + OFF_WST);
  us16* WSAT  = (us16*)(ws + OFF_WSAT);
  us16* WKVST = (us16*)(ws + OFF_WKVST);
  us16* WC1T  = (us16*)(ws + OFF_WC1T);
  us16* WV1T  = (us16*)(ws + OFF_WV1T);
  us16* ENC   = (us16*)(ws + OFF_ENC);    // sa_enc, later reused for s_enc
  us16* OTHER = (us16*)(ws + OFF_OTHER);
  us16* KSV   = (us16*)(ws + OFF_KSV);    // one head at a time: [b][n][384]
  float* PART = (float*)(ws + OFF_PART);

  dim3 tb(32, 8);
  tconv_k<<<dim3(2, 16, 8),  tb, 0, stream>>>(Ws,  (long)64 * 512,  64,  512, WST,  (long)512 * 64,  0,   64,   64);
  tconv_k<<<dim3(3, 16, 8),  tb, 0, stream>>>(Wsa, (long)80 * 512,  80,  512, WSAT, (long)512 * 96,  0,   96,   96);
  tconv_k<<<dim3(16, 4, 4),  tb, 0, stream>>>(Wk,  (long)512 * 128, 512, 128, WKVST,(long)384 * 512, 0,   512,  512);
  tconv_k<<<dim3(16, 4, 4),  tb, 0, stream>>>(Wsel,(long)512 * 128, 512, 128, WKVST,(long)384 * 512, 128, 512,  512);
  tconv_k<<<dim3(16, 4, 4),  tb, 0, stream>>>(Wv,  (long)512 * 128, 512, 128, WKVST,(long)384 * 512, 256, 512,  512);
  tconv_k<<<dim3(32, 16, 8), tb, 0, stream>>>(Wc1, (long)1024 * 512,1024,512, WC1T, (long)512 * 1024,0,   1024, 1024);
  tconv_k<<<dim3(32, 16, 8), tb, 0, stream>>>(Wv1, (long)1024 * 512,1024,512, WV1T, (long)512 * 1024,0,   1024, 1024);

  // sa_enc = lrelu([states|actions] @ Wsa + bsa)  -> ENC (bf16)
  gemm_k<ASRC_F32_CAT, EPI_STORE, 96><<<dim3(64, 4, 8), 256, 0, stream>>>(
      states, (long)8192 * 64, actions, (long)8192 * 16, WSAT, (long)512 * 96, bsa, 512,
      ENC, (long)8192 * 512, 512, nullptr, nullptr);

  // per head: ksv = sa_enc @ [Wk|Wsel|Wv] (+bv,lrelu on vals), then attention
  for (int e = 0; e < 4; e++) {
    gemm_k<ASRC_BF16, EPI_KSV, 512><<<dim3(64, 3, 8), 256, 0, stream>>>(
        ENC, (long)8192 * 512, nullptr, 0, WKVST + (size_t)e * 384 * 512, 0, bv + e * 128, 0,
        KSV, 384, 3072, nullptr, nullptr);
    attn_k<<<dim3(2048), 256, 0, stream>>>(KSV, OTHER, e);
  }

  // q = lrelu([sa_enc|other] @ Wc1 + bc1) @ Wc2 + bc2
  gemm_k<ASRC_BF16_CAT, EPI_DOT, 1024><<<dim3(64, 4, 8), 256, 0, stream>>>(
      ENC, (long)8192 * 512, OTHER, (long)8192 * 512, WC1T, (long)512 * 1024, bc1, 512,
      nullptr, 0, 0, Wc2, PART);
  reduce_dot_k<<<dim3(256), 256, 0, stream>>>(PART, bc2, (float*)d_out);

  // s_enc = lrelu(states @ Ws + bs) -> ENC (sa_enc is dead now)
  gemm_k<ASRC_F32, EPI_STORE, 64><<<dim3(64, 4, 8), 256, 0, stream>>>(
      states, (long)8192 * 64, nullptr, 0, WST, (long)512 * 64, bs, 512,
      ENC, (long)8192 * 512, 512, nullptr, nullptr);

  // v = lrelu([s_enc|other] @ Wv1 + bv1) @ Wv2 + bv2
  gemm_k<ASRC_BF16_CAT, EPI_DOT, 1024><<<dim3(64, 4, 8), 256, 0, stream>>>(
      ENC, (long)8192 * 512, OTHER, (long)8192 * 512, WV1T, (long)512 * 1024, bv1, 512,
      nullptr, 0, 0, Wv2, PART);
  reduce_dot_k<<<dim3(256), 256, 0, stream>>>(PART, bv2, (float*)d_out + 65536);
}

// Round 2
// 470.990 us; speedup vs baseline: 1.0652x; 1.0652x over previous
//
#include <hip/hip_runtime.h>

// ---------------------------------------------------------------------------
// AttentionCritic on MI355X — round 2: global_load_lds (m97 structure).
// N=8 agents, B=8192, S=64, A=16, H=512, E=4 heads, D=128.
// ---------------------------------------------------------------------------

#define DEVI __device__ __forceinline__

typedef unsigned short us16;
typedef __bf16 bf16x8 __attribute__((ext_vector_type(8)));
typedef float f32x4 __attribute__((ext_vector_type(4)));
typedef unsigned short u16x8 __attribute__((ext_vector_type(8)));

DEVI us16 f2bf(float f) {
  unsigned u = __builtin_bit_cast(unsigned, f);
  u += 0x7FFFu + ((u >> 16) & 1u);          // round-to-nearest-even
  return (us16)(u >> 16);
}
DEVI float bf2f(us16 h) {
  unsigned u = ((unsigned)h) << 16;
  return __builtin_bit_cast(float, u);
}
DEVI float lrelu(float v) { return v > 0.f ? v : 0.01f * v; }
DEVI int pk2(float a, float b) { return (int)f2bf(a) | ((int)f2bf(b) << 16); }

// async global->LDS, 16B per lane. LDS dest must be linear: base + lane*16.
DEVI void gload16(const us16* g, us16* l) {
  __builtin_amdgcn_global_load_lds(
      (const __attribute__((address_space(1))) void*)g,
      (__attribute__((address_space(3))) void*)l, 16, 0, 0);
}

// ---------------------------------------------------------------------------
// Transpose + fp32->bf16 convert:  dst[s][dstRowOff+o][k] = src[s][k][o] (k<K else 0)
// block (32,8), grid (Kpad/32, ceil(O/32), slices)
// ---------------------------------------------------------------------------
__global__ void tconv_k(const float* __restrict__ src, long srcSlice, int K, int O,
                        us16* __restrict__ dst, long dstSlice, int dstRowOff,
                        int ldd, int Kpad)
{
  __shared__ float t[32][33];
  const int s = blockIdx.z;
  const int k0 = blockIdx.x * 32, o0 = blockIdx.y * 32;
  const int lx = threadIdx.x, ly = threadIdx.y;
#pragma unroll
  for (int i = 0; i < 4; i++) {
    int k = k0 + ly + i * 8, o = o0 + lx;
    float v = 0.f;
    if (k < K && o < O) v = src[(long)s * srcSlice + (long)k * O + o];
    t[ly + i * 8][lx] = v;
  }
  __syncthreads();
#pragma unroll
  for (int i = 0; i < 4; i++) {
    int o = o0 + ly + i * 8, k = k0 + lx;
    if (o < O && k < Kpad)
      dst[(long)s * dstSlice + (long)(dstRowOff + o) * ldd + k] = f2bf(t[lx][ly + i * 8]);
  }
}

// ---------------------------------------------------------------------------
// MFMA GEMM: C[8192 x N] = A[8192 x K] * Bt[N x K]^T (+bias, lrelu, ...)
// 128x128 tile, 256 threads = 4 waves (2x2 of 64x64), BK=32.
// Staging via global_load_lds width 16 into LINEAR LDS [128][32].
// fp32-A paths reg-stage A (convert to bf16) but use gload for B.
// ---------------------------------------------------------------------------
enum { ASRC_BF16 = 0, ASRC_BF16_CAT = 1, ASRC_F32 = 2, ASRC_F32_CAT = 3 };
enum { EPI_STORE = 0, EPI_KSV = 1, EPI_DOT = 2 };

template <int ASRC, int EPI, int KTOT>
__global__ __launch_bounds__(256, 4)
void gemm_k(const void* __restrict__ Ap, long aSlice,
            const void* __restrict__ A2p, long a2Slice,
            const us16* __restrict__ Btp, long bSlice,
            const float* __restrict__ bias, long biasSlice,
            us16* __restrict__ outB, long outSlice, long outRow,
            const float* __restrict__ dotW, float* __restrict__ partial)
{
  __shared__ us16 lA[128 * 32];   // linear — required by global_load_lds
  __shared__ us16 lB[128 * 32];
  const int tid = threadIdx.x;
  const int z = blockIdx.z;
  const int m0 = blockIdx.x * 128;
  const int n0 = blockIdx.y * 128;
  const int wv = tid >> 6, lane = tid & 63;
  const int wm = (wv >> 1) * 64, wn = (wv & 1) * 64;
  const int fr = lane & 15, fk = (lane >> 4) * 8;
  const int rbase = (lane >> 4) * 4;
  // gload chunk map: thread t covers (row t>>2, cols (t&3)*8..+8); 2 calls = 128 rows
  const int grow = tid >> 2, gcol = (tid & 3) * 8;

  f32x4 acc[4][4];
#pragma unroll
  for (int i = 0; i < 4; i++)
#pragma unroll
    for (int j = 0; j < 4; j++) acc[i][j] = f32x4{0.f, 0.f, 0.f, 0.f};

  const us16* bbase = Btp + (long)z * bSlice + (long)n0 * KTOT;

  for (int k0 = 0; k0 < KTOT; k0 += 32) {
    int4 ra0, ra1;
    if constexpr (ASRC == ASRC_F32 || ASRC == ASRC_F32_CAT) {
      const int srow = tid >> 1, scol0 = (tid & 1) * 16;
      const int kg = k0 + scol0;
      const float* a = nullptr;
      if constexpr (ASRC == ASRC_F32) {
        a = (const float*)Ap + (long)z * aSlice + (long)(m0 + srow) * 64 + kg;
      } else {  // states(0..63) | actions(64..79) | zero pad(80..95)
        if (kg < 64)      a = (const float*)Ap + (long)z * aSlice + (long)(m0 + srow) * 64 + kg;
        else if (kg < 80) a = (const float*)A2p + (long)z * a2Slice + (long)(m0 + srow) * 16 + (kg - 64);
      }
      float4 f0, f1, f2, f3;
      if (a) { const float4* ap = (const float4*)a; f0 = ap[0]; f1 = ap[1]; f2 = ap[2]; f3 = ap[3]; }
      else   { f0 = make_float4(0.f, 0.f, 0.f, 0.f); f1 = f0; f2 = f0; f3 = f0; }
      ra0.x = pk2(f0.x, f0.y); ra0.y = pk2(f0.z, f0.w); ra0.z = pk2(f1.x, f1.y); ra0.w = pk2(f1.z, f1.w);
      ra1.x = pk2(f2.x, f2.y); ra1.y = pk2(f2.z, f2.w); ra1.z = pk2(f3.x, f3.y); ra1.w = pk2(f3.z, f3.w);
    }

    __syncthreads();   // previous iteration's LDS reads complete

    {  // B: 2 gload calls (rows grow and 64+grow)
      const us16* bb = bbase + k0 + gcol;
      gload16(bb + (long)grow * KTOT, &lB[tid * 8]);
      gload16(bb + (long)(64 + grow) * KTOT, &lB[2048 + tid * 8]);
    }
    if constexpr (ASRC == ASRC_BF16) {
      const us16* ab = (const us16*)Ap + (long)z * aSlice + (long)m0 * KTOT + k0 + gcol;
      gload16(ab + (long)grow * KTOT, &lA[tid * 8]);
      gload16(ab + (long)(64 + grow) * KTOT, &lA[2048 + tid * 8]);
    } else if constexpr (ASRC == ASRC_BF16_CAT) {
      const int kg = k0 + gcol;   // 8-chunks never straddle the 512 boundary
      const us16* base = (kg < 512)
          ? (const us16*)Ap  + (long)z * aSlice  + kg
          : (const us16*)A2p + (long)z * a2Slice + (kg - 512);
      gload16(base + (long)(m0 + grow) * 512, &lA[tid * 8]);
      gload16(base + (long)(m0 + 64 + grow) * 512, &lA[2048 + tid * 8]);
    } else {
      const int srow = tid >> 1, scol0 = (tid & 1) * 16;
      *(int4*)&lA[srow * 32 + scol0]     = ra0;
      *(int4*)&lA[srow * 32 + scol0 + 8] = ra1;
    }

    __syncthreads();   // drains vmcnt(0)+lgkmcnt(0): staging complete

    bf16x8 af[4], bfg[4];
#pragma unroll
    for (int f = 0; f < 4; f++) af[f]  = *(const bf16x8*)&lA[(wm + f * 16 + fr) * 32 + fk];
#pragma unroll
    for (int f = 0; f < 4; f++) bfg[f] = *(const bf16x8*)&lB[(wn + f * 16 + fr) * 32 + fk];
#pragma unroll
    for (int fm = 0; fm < 4; fm++)
#pragma unroll
      for (int fn = 0; fn < 4; fn++)
        acc[fm][fn] = __builtin_amdgcn_mfma_f32_16x16x32_bf16(af[fm], bfg[fn], acc[fm][fn], 0, 0, 0);
  }

  if constexpr (EPI == EPI_DOT) {
    // hidden = lrelu(acc + bc1[col]); partial[row] += hidden * W2[col]
    const float* bsl = bias + (long)z * 512;
    const float* wsl = dotW + (long)z * 512;
#pragma unroll
    for (int fm = 0; fm < 4; fm++) {
#pragma unroll
      for (int j = 0; j < 4; j++) {
        float p = 0.f;
#pragma unroll
        for (int fn = 0; fn < 4; fn++) {
          int col = n0 + wn + fn * 16 + fr;
          float v = acc[fm][fn][j] + bsl[col];
          v = lrelu(v);
          p += v * wsl[col];
        }
        p += __shfl_xor(p, 1); p += __shfl_xor(p, 2); p += __shfl_xor(p, 4); p += __shfl_xor(p, 8);
        if (fr == 0) {
          long row = (long)z * 8192 + (m0 + wm + fm * 16 + rbase + j);
          partial[row * 8 + blockIdx.y * 2 + (wv & 1)] = p;
        }
      }
    }
  } else {
#pragma unroll
    for (int fm = 0; fm < 4; fm++) {
#pragma unroll
      for (int fn = 0; fn < 4; fn++) {
        int col = n0 + wn + fn * 16 + fr;
        float badd = 0.f; bool act = false;
        if constexpr (EPI == EPI_STORE) { badd = bias[(long)z * biasSlice + col]; act = true; }
        else { if (col >= 256) { badd = bias[col - 256]; act = true; } }  // vals third only
        us16* op = outB + (long)z * outSlice + (long)(m0 + wm + fm * 16 + rbase) * outRow + col;
#pragma unroll
        for (int j = 0; j < 4; j++) {
          float v = acc[fm][fn][j] + badd;
          if (act) v = lrelu(v);
          op[(long)j * outRow] = f2bf(v);
        }
      }
    }
  }
}

// ---------------------------------------------------------------------------
// Attention: per (b,e): logits = sel_i . key_j / sqrt(128); softmax_j; PV.
// KSV layout [b][n][384] (cols: 0-127 key, 128-255 sel, 256-383 val).
// One wave per b; 4 waves/block; LDS rows padded to 392 (conflict-free dots).
// ---------------------------------------------------------------------------
__global__ __launch_bounds__(256, 2)
void attn_k(const us16* __restrict__ ksv, us16* __restrict__ other, int e)
{
  __shared__ us16 t[4][8 * 392];
  const int wv = threadIdx.x >> 6, lane = threadIdx.x & 63;
  const long b = (long)blockIdx.x * 4 + wv;
  const us16* src = ksv + b * 3072;
#pragma unroll
  for (int i = 0; i < 6; i++) {
    int c = i * 64 + lane;                 // 384 16B-chunks (8 rows x 48)
    int r = c / 48, cc = c - r * 48;
    *(int4*)&t[wv][r * 392 + cc * 8] = *(const int4*)&src[c * 8];
  }
  __syncthreads();
  const int i = lane >> 3, j = lane & 7;   // lane = i*8 + j
  const us16* selp = &t[wv][i * 392 + 128];
  const us16* keyp = &t[wv][j * 392];
  float acc = 0.f;
#pragma unroll
  for (int d = 0; d < 128; d += 8) {
    u16x8 s8 = *(const u16x8*)&selp[d];
    u16x8 k8 = *(const u16x8*)&keyp[d];
#pragma unroll
    for (int q = 0; q < 8; q++) acc += bf2f(s8[q]) * bf2f(k8[q]);
  }
  acc *= 0.088388347648318447f;            // 1/sqrt(128)
  float mx = acc;
  mx = fmaxf(mx, __shfl_xor(mx, 1)); mx = fmaxf(mx, __shfl_xor(mx, 2)); mx = fmaxf(mx, __shfl_xor(mx, 4));
  float ex = __expf(acc - mx);
  float sm = ex;
  sm += __shfl_xor(sm, 1); sm += __shfl_xor(sm, 2); sm += __shfl_xor(sm, 4);
  float wsm = ex / sm;
  float wj[8];
  const int ibase = lane & 56;
#pragma unroll
  for (int jj = 0; jj < 8; jj++) wj[jj] = __shfl(wsm, ibase + jj);
  const int dbase = (lane & 7) * 16;       // this lane: agent i, dims dbase..dbase+15
  float o[16];
#pragma unroll
  for (int q = 0; q < 16; q++) o[q] = 0.f;
#pragma unroll
  for (int jj = 0; jj < 8; jj++) {
    u16x8 v0 = *(const u16x8*)&t[wv][jj * 392 + 256 + dbase];
    u16x8 v1 = *(const u16x8*)&t[wv][jj * 392 + 256 + dbase + 8];
    float wgt = wj[jj];
#pragma unroll
    for (int q = 0; q < 8; q++) { o[q] += wgt * bf2f(v0[q]); o[8 + q] += wgt * bf2f(v1[q]); }
  }
  u16x8 r0, r1;
#pragma unroll
  for (int q = 0; q < 8; q++) { r0[q] = f2bf(o[q]); r1[q] = f2bf(o[8 + q]); }
  us16* dst = other + ((long)i * 8192 + b) * 512 + e * 128 + dbase;
  *(u16x8*)&dst[0] = r0;
  *(u16x8*)&dst[8] = r1;
}

// q[r] = b2[r>>13] + sum of 8 per-block partials
__global__ void reduce_dot_k(const float* __restrict__ part, const float* __restrict__ b2,
                             float* __restrict__ out)
{
  int r = blockIdx.x * 256 + threadIdx.x;  // 0..65535
  const float4* p = (const float4*)(part + (long)r * 8);
  float4 a = p[0], b = p[1];
  out[r] = b2[r >> 13] + ((a.x + a.y) + (a.z + a.w)) + ((b.x + b.y) + (b.z + b.w));
}

// ---------------------------------------------------------------------------
extern "C" void kernel_launch(void* const* d_in, const int* in_sizes, int n_in,
                              void* d_out, int out_size, void* d_ws, size_t ws_size,
                              hipStream_t stream)
{
  const float* states = (const float*)d_in[0];
  const float* actions= (const float*)d_in[1];
  const float* Ws  = (const float*)d_in[2];
  const float* bs  = (const float*)d_in[3];
  const float* Wsa = (const float*)d_in[4];
  const float* bsa = (const float*)d_in[5];
  const float* Wk  = (const float*)d_in[6];
  const float* Wsel= (const float*)d_in[7];
  const float* Wv  = (const float*)d_in[8];
  const float* bv  = (const float*)d_in[9];
  const float* Wc1 = (const float*)d_in[10];
  const float* bc1 = (const float*)d_in[11];
  const float* Wc2 = (const float*)d_in[12];
  const float* bc2 = (const float*)d_in[13];
  const float* Wv1 = (const float*)d_in[14];
  const float* bv1 = (const float*)d_in[15];
  const float* Wv2 = (const float*)d_in[16];
  const float* bv2 = (const float*)d_in[17];

  char* ws = (char*)d_ws;
  constexpr size_t OFF_WST   = 0;
  constexpr size_t OFF_WSAT  = OFF_WST   + (size_t)8 * 512 * 64 * 2;
  constexpr size_t OFF_WKVST = OFF_WSAT  + (size_t)8 * 512 * 96 * 2;
  constexpr size_t OFF_WC1T  = OFF_WKVST + (size_t)4 * 384 * 512 * 2;
  constexpr size_t OFF_WV1T  = OFF_WC1T  + (size_t)8 * 512 * 1024 * 2;
  constexpr size_t OFF_ENC   = OFF_WV1T  + (size_t)8 * 512 * 1024 * 2;
  constexpr size_t OFF_OTHER = OFF_ENC   + (size_t)8 * 8192 * 512 * 2;
  constexpr size_t OFF_KSV   = OFF_OTHER + (size_t)8 * 8192 * 512 * 2;
  constexpr size_t OFF_PART  = OFF_KSV   + (size_t)8192 * 8 * 384 * 2;
  constexpr size_t NEED      = OFF_PART  + (size_t)65536 * 8 * 4;
  if (ws_size < NEED) return;  // workspace too small -> loud validation failure

  us16* WST   = (us16*)(ws + OFF_WST);
  us16* WSAT  = (us16*)(ws + OFF_WSAT);
  us16* WKVST = (us16*)(ws + OFF_WKVST);
  us16* WC1T  = (us16*)(ws + OFF_WC1T);
  us16* WV1T  = (us16*)(ws + OFF_WV1T);
  us16* ENC   = (us16*)(ws + OFF_ENC);    // sa_enc, later reused for s_enc
  us16* OTHER = (us16*)(ws + OFF_OTHER);
  us16* KSV   = (us16*)(ws + OFF_KSV);    // one head at a time: [b][n][384]
  float* PART = (float*)(ws + OFF_PART);

  dim3 tb(32, 8);
  tconv_k<<<dim3(2, 16, 8),  tb, 0, stream>>>(Ws,  (long)64 * 512,  64,  512, WST,  (long)512 * 64,  0,   64,   64);
  tconv_k<<<dim3(3, 16, 8),  tb, 0, stream>>>(Wsa, (long)80 * 512,  80,  512, WSAT, (long)512 * 96,  0,   96,   96);
  tconv_k<<<dim3(16, 4, 4),  tb, 0, stream>>>(Wk,  (long)512 * 128, 512, 128, WKVST,(long)384 * 512, 0,   512,  512);
  tconv_k<<<dim3(16, 4, 4),  tb, 0, stream>>>(Wsel,(long)512 * 128, 512, 128, WKVST,(long)384 * 512, 128, 512,  512);
  tconv_k<<<dim3(16, 4, 4),  tb, 0, stream>>>(Wv,  (long)512 * 128, 512, 128, WKVST,(long)384 * 512, 256, 512,  512);
  tconv_k<<<dim3(32, 16, 8), tb, 0, stream>>>(Wc1, (long)1024 * 512,1024,512, WC1T, (long)512 * 1024,0,   1024, 1024);
  tconv_k<<<dim3(32, 16, 8), tb, 0, stream>>>(Wv1, (long)1024 * 512,1024,512, WV1T, (long)512 * 1024,0,   1024, 1024);

  // sa_enc = lrelu([states|actions] @ Wsa + bsa)  -> ENC (bf16)
  gemm_k<ASRC_F32_CAT, EPI_STORE, 96><<<dim3(64, 4, 8), 256, 0, stream>>>(
      states, (long)8192 * 64, actions, (long)8192 * 16, WSAT, (long)512 * 96, bsa, 512,
      ENC, (long)8192 * 512, 512, nullptr, nullptr);

  // per head: ksv = sa_enc @ [Wk|Wsel|Wv] (+bv,lrelu on vals), then attention
  for (int e = 0; e < 4; e++) {
    gemm_k<ASRC_BF16, EPI_KSV, 512><<<dim3(64, 3, 8), 256, 0, stream>>>(
        ENC, (long)8192 * 512, nullptr, 0, WKVST + (size_t)e * 384 * 512, 0, bv + e * 128, 0,
        KSV, 384, 3072, nullptr, nullptr);
    attn_k<<<dim3(2048), 256, 0, stream>>>(KSV, OTHER, e);
  }

  // q = lrelu([sa_enc|other] @ Wc1 + bc1) @ Wc2 + bc2
  gemm_k<ASRC_BF16_CAT, EPI_DOT, 1024><<<dim3(64, 4, 8), 256, 0, stream>>>(
      ENC, (long)8192 * 512, OTHER, (long)8192 * 512, WC1T, (long)512 * 1024, bc1, 512,
      nullptr, 0, 0, Wc2, PART);
  reduce_dot_k<<<dim3(256), 256, 0, stream>>>(PART, bc2, (float*)d_out);

  // s_enc = lrelu(states @ Ws + bs) -> ENC (sa_enc is dead now)
  gemm_k<ASRC_F32, EPI_STORE, 64><<<dim3(64, 4, 8), 256, 0, stream>>>(
      states, (long)8192 * 64, nullptr, 0, WST, (long)512 * 64, bs, 512,
      ENC, (long)8192 * 512, 512, nullptr, nullptr);

  // v = lrelu([s_enc|other] @ Wv1 + bv1) @ Wv2 + bv2
  gemm_k<ASRC_BF16_CAT, EPI_DOT, 1024><<<dim3(64, 4, 8), 256, 0, stream>>>(
      ENC, (long)8192 * 512, OTHER, (long)8192 * 512, WV1T, (long)512 * 1024, bv1, 512,
      nullptr, 0, 0, Wv2, PART);
  reduce_dot_k<<<dim3(256), 256, 0, stream>>>(PART, bv2, (float*)d_out + 65536);
}

// Round 3
// 436.908 us; speedup vs baseline: 1.1483x; 1.0780x over previous
//
#include <hip/hip_runtime.h>

// ---------------------------------------------------------------------------
// AttentionCritic on MI355X — round 3: BK=64 + XOR-swizzled LDS (T2) for the
// bf16 MFMA GEMMs; fp32 encoder GEMMs keep the round-2 path.
// N=8 agents, B=8192, S=64, A=16, H=512, E=4 heads, D=128.
// ---------------------------------------------------------------------------

#define DEVI __device__ __forceinline__

typedef unsigned short us16;
typedef __bf16 bf16x8 __attribute__((ext_vector_type(8)));
typedef float f32x4 __attribute__((ext_vector_type(4)));
typedef unsigned short u16x8 __attribute__((ext_vector_type(8)));

DEVI us16 f2bf(float f) {
  unsigned u = __builtin_bit_cast(unsigned, f);
  u += 0x7FFFu + ((u >> 16) & 1u);          // round-to-nearest-even
  return (us16)(u >> 16);
}
DEVI float bf2f(us16 h) {
  unsigned u = ((unsigned)h) << 16;
  return __builtin_bit_cast(float, u);
}
DEVI float lrelu(float v) { return v > 0.f ? v : 0.01f * v; }
DEVI int pk2(float a, float b) { return (int)f2bf(a) | ((int)f2bf(b) << 16); }

// async global->LDS, 16B per lane. LDS dest must be linear: base + lane*16.
DEVI void gload16(const us16* g, us16* l) {
  __builtin_amdgcn_global_load_lds(
      (const __attribute__((address_space(1))) void*)g,
      (__attribute__((address_space(3))) void*)l, 16, 0, 0);
}

// ---------------------------------------------------------------------------
// Transpose + fp32->bf16 convert:  dst[s][dstRowOff+o][k] = src[s][k][o] (k<K else 0)
// block (32,8), grid (Kpad/32, ceil(O/32), slices)
// ---------------------------------------------------------------------------
__global__ void tconv_k(const float* __restrict__ src, long srcSlice, int K, int O,
                        us16* __restrict__ dst, long dstSlice, int dstRowOff,
                        int ldd, int Kpad)
{
  __shared__ float t[32][33];
  const int s = blockIdx.z;
  const int k0 = blockIdx.x * 32, o0 = blockIdx.y * 32;
  const int lx = threadIdx.x, ly = threadIdx.y;
#pragma unroll
  for (int i = 0; i < 4; i++) {
    int k = k0 + ly + i * 8, o = o0 + lx;
    float v = 0.f;
    if (k < K && o < O) v = src[(long)s * srcSlice + (long)k * O + o];
    t[ly + i * 8][lx] = v;
  }
  __syncthreads();
#pragma unroll
  for (int i = 0; i < 4; i++) {
    int o = o0 + ly + i * 8, k = k0 + lx;
    if (o < O && k < Kpad)
      dst[(long)s * dstSlice + (long)(dstRowOff + o) * ldd + k] = f2bf(t[lx][ly + i * 8]);
  }
}

// ---------------------------------------------------------------------------
// fp32-input encoder GEMM (round-2 structure, BK=32, linear LDS).
// C[8192 x 512] = A[8192 x K] * Bt[512 x K]^T, bias + lrelu, bf16 store.
// ---------------------------------------------------------------------------
enum { ASRC_F32 = 2, ASRC_F32_CAT = 3 };

template <int ASRC, int KTOT>
__global__ __launch_bounds__(256, 4)
void enc_gemm_k(const float* __restrict__ Ap, long aSlice,
                const float* __restrict__ A2p, long a2Slice,
                const us16* __restrict__ Btp, long bSlice,
                const float* __restrict__ bias, long biasSlice,
                us16* __restrict__ outB, long outSlice, long outRow)
{
  __shared__ us16 lA[128 * 32];   // linear — required by global_load_lds
  __shared__ us16 lB[128 * 32];
  const int tid = threadIdx.x;
  const int z = blockIdx.z;
  const int m0 = blockIdx.x * 128;
  const int n0 = blockIdx.y * 128;
  const int wv = tid >> 6, lane = tid & 63;
  const int wm = (wv >> 1) * 64, wn = (wv & 1) * 64;
  const int fr = lane & 15, fk = (lane >> 4) * 8;
  const int rbase = (lane >> 4) * 4;
  const int grow = tid >> 2, gcol = (tid & 3) * 8;

  f32x4 acc[4][4];
#pragma unroll
  for (int i = 0; i < 4; i++)
#pragma unroll
    for (int j = 0; j < 4; j++) acc[i][j] = f32x4{0.f, 0.f, 0.f, 0.f};

  const us16* bbase = Btp + (long)z * bSlice + (long)n0 * KTOT;

  for (int k0 = 0; k0 < KTOT; k0 += 32) {
    int4 ra0, ra1;
    {
      const int srow = tid >> 1, scol0 = (tid & 1) * 16;
      const int kg = k0 + scol0;
      const float* a = nullptr;
      if constexpr (ASRC == ASRC_F32) {
        a = Ap + (long)z * aSlice + (long)(m0 + srow) * 64 + kg;
      } else {  // states(0..63) | actions(64..79) | zero pad(80..95)
        if (kg < 64)      a = Ap + (long)z * aSlice + (long)(m0 + srow) * 64 + kg;
        else if (kg < 80) a = A2p + (long)z * a2Slice + (long)(m0 + srow) * 16 + (kg - 64);
      }
      float4 f0, f1, f2, f3;
      if (a) { const float4* ap = (const float4*)a; f0 = ap[0]; f1 = ap[1]; f2 = ap[2]; f3 = ap[3]; }
      else   { f0 = make_float4(0.f, 0.f, 0.f, 0.f); f1 = f0; f2 = f0; f3 = f0; }
      ra0.x = pk2(f0.x, f0.y); ra0.y = pk2(f0.z, f0.w); ra0.z = pk2(f1.x, f1.y); ra0.w = pk2(f1.z, f1.w);
      ra1.x = pk2(f2.x, f2.y); ra1.y = pk2(f2.z, f2.w); ra1.z = pk2(f3.x, f3.y); ra1.w = pk2(f3.z, f3.w);
    }

    __syncthreads();
    {
      const us16* bb = bbase + k0 + gcol;
      gload16(bb + (long)grow * KTOT, &lB[tid * 8]);
      gload16(bb + (long)(64 + grow) * KTOT, &lB[2048 + tid * 8]);
    }
    {
      const int srow = tid >> 1, scol0 = (tid & 1) * 16;
      *(int4*)&lA[srow * 32 + scol0]     = ra0;
      *(int4*)&lA[srow * 32 + scol0 + 8] = ra1;
    }
    __syncthreads();

    bf16x8 af[4], bfg[4];
#pragma unroll
    for (int f = 0; f < 4; f++) af[f]  = *(const bf16x8*)&lA[(wm + f * 16 + fr) * 32 + fk];
#pragma unroll
    for (int f = 0; f < 4; f++) bfg[f] = *(const bf16x8*)&lB[(wn + f * 16 + fr) * 32 + fk];
#pragma unroll
    for (int fm = 0; fm < 4; fm++)
#pragma unroll
      for (int fn = 0; fn < 4; fn++)
        acc[fm][fn] = __builtin_amdgcn_mfma_f32_16x16x32_bf16(af[fm], bfg[fn], acc[fm][fn], 0, 0, 0);
  }

#pragma unroll
  for (int fm = 0; fm < 4; fm++) {
#pragma unroll
    for (int fn = 0; fn < 4; fn++) {
      int col = n0 + wn + fn * 16 + fr;
      float badd = bias[(long)z * biasSlice + col];
      us16* op = outB + (long)z * outSlice + (long)(m0 + wm + fm * 16 + rbase) * outRow + col;
#pragma unroll
      for (int j = 0; j < 4; j++) {
        float v = lrelu(acc[fm][fn][j] + badd);
        op[(long)j * outRow] = f2bf(v);
      }
    }
  }
}

// ---------------------------------------------------------------------------
// bf16 MFMA GEMM, BK=64, XOR-swizzled LDS (T2, rule-21 both-sides pattern):
//   staging: linear gload dest, source col = ((chunk ^ (row&7)) << 3)
//   reads:   elem addr = row*64 + ((k_col) ^ ((row&7)<<3))
// 128x128 tile, 4 waves, 32 MFMA per barrier pair.
// CAT: A = [Ap row-512 | A2p row-512] concatenated along K (KTOT=1024).
// ---------------------------------------------------------------------------
enum { EPI_KSV = 1, EPI_DOT = 2 };

template <bool CAT, int EPI, int KTOT>
__global__ __launch_bounds__(256, 4)
void gemm64_k(const us16* __restrict__ Ap, long aSlice,
              const us16* __restrict__ A2p, long a2Slice,
              const us16* __restrict__ Btp, long bSlice,
              const float* __restrict__ bias,
              us16* __restrict__ outB, long outSlice, long outRow,
              const float* __restrict__ dotW, float* __restrict__ partial)
{
  __shared__ us16 lA[128 * 64];
  __shared__ us16 lB[128 * 64];
  const int tid = threadIdx.x;
  const int z = blockIdx.z;
  const int m0 = blockIdx.x * 128;
  const int n0 = blockIdx.y * 128;
  const int wv = tid >> 6, lane = tid & 63;
  const int wm = (wv >> 1) * 64, wn = (wv & 1) * 64;
  const int fr = lane & 15, fk = (lane >> 4) * 8;
  const int rbase = (lane >> 4) * 4;
  const int xorkey = (fr & 7) << 3;     // read-side swizzle key (elements)

  f32x4 acc[4][4];
#pragma unroll
  for (int i = 0; i < 4; i++)
#pragma unroll
    for (int j = 0; j < 4; j++) acc[i][j] = f32x4{0.f, 0.f, 0.f, 0.f};

  const us16* bbase = Btp + (long)z * bSlice + (long)n0 * KTOT;

  for (int k0 = 0; k0 < KTOT; k0 += 64) {
    __syncthreads();   // previous iteration's LDS reads complete
#pragma unroll
    for (int i = 0; i < 4; i++) {
      const int c = i * 256 + tid;            // 16B chunk index, 0..1023
      const int r = c >> 3;                   // tile row 0..127
      const int col = ((c & 7) ^ (r & 7)) << 3;  // inverse-swizzled source col
      const us16* a;
      if constexpr (!CAT) {
        a = Ap + (long)z * aSlice + (long)(m0 + r) * KTOT + (k0 + col);
      } else {
        const int kg = k0 + col;              // 8-elem chunks never straddle 512
        a = (kg < 512) ? Ap  + (long)z * aSlice  + (long)(m0 + r) * 512 + kg
                       : A2p + (long)z * a2Slice + (long)(m0 + r) * 512 + (kg - 512);
      }
      gload16(a, &lA[c * 8]);
    }
#pragma unroll
    for (int i = 0; i < 4; i++) {
      const int c = i * 256 + tid;
      const int r = c >> 3;
      const int col = ((c & 7) ^ (r & 7)) << 3;
      gload16(bbase + (long)r * KTOT + (k0 + col), &lB[c * 8]);
    }
    __syncthreads();   // drains vmcnt(0): staging complete

#pragma unroll
    for (int ks = 0; ks < 2; ks++) {
      bf16x8 af[4], bfg[4];
      const int kc = ks * 32 + fk;
#pragma unroll
      for (int f = 0; f < 4; f++)
        af[f]  = *(const bf16x8*)&lA[(wm + f * 16 + fr) * 64 + (kc ^ xorkey)];
#pragma unroll
      for (int f = 0; f < 4; f++)
        bfg[f] = *(const bf16x8*)&lB[(wn + f * 16 + fr) * 64 + (kc ^ xorkey)];
#pragma unroll
      for (int fm = 0; fm < 4; fm++)
#pragma unroll
        for (int fn = 0; fn < 4; fn++)
          acc[fm][fn] = __builtin_amdgcn_mfma_f32_16x16x32_bf16(af[fm], bfg[fn], acc[fm][fn], 0, 0, 0);
    }
  }

  if constexpr (EPI == EPI_DOT) {
    // hidden = lrelu(acc + bc1[col]); partial[row] += hidden * W2[col]
    const float* bsl = bias + (long)z * 512;
    const float* wsl = dotW + (long)z * 512;
#pragma unroll
    for (int fm = 0; fm < 4; fm++) {
#pragma unroll
      for (int j = 0; j < 4; j++) {
        float p = 0.f;
#pragma unroll
        for (int fn = 0; fn < 4; fn++) {
          int col = n0 + wn + fn * 16 + fr;
          float v = acc[fm][fn][j] + bsl[col];
          v = lrelu(v);
          p += v * wsl[col];
        }
        p += __shfl_xor(p, 1); p += __shfl_xor(p, 2); p += __shfl_xor(p, 4); p += __shfl_xor(p, 8);
        if (fr == 0) {
          long row = (long)z * 8192 + (m0 + wm + fm * 16 + rbase + j);
          partial[row * 8 + blockIdx.y * 2 + (wv & 1)] = p;
        }
      }
    }
  } else {
    // KSV: cols 0-255 raw (key|sel), cols 256-383 get bias+lrelu (vals)
#pragma unroll
    for (int fm = 0; fm < 4; fm++) {
#pragma unroll
      for (int fn = 0; fn < 4; fn++) {
        int col = n0 + wn + fn * 16 + fr;
        float badd = 0.f; bool act = false;
        if (col >= 256) { badd = bias[col - 256]; act = true; }
        us16* op = outB + (long)z * outSlice + (long)(m0 + wm + fm * 16 + rbase) * outRow + col;
#pragma unroll
        for (int j = 0; j < 4; j++) {
          float v = acc[fm][fn][j] + badd;
          if (act) v = lrelu(v);
          op[(long)j * outRow] = f2bf(v);
        }
      }
    }
  }
}

// ---------------------------------------------------------------------------
// Attention: per (b,e): logits = sel_i . key_j / sqrt(128); softmax_j; PV.
// KSV layout [b][n][384] (cols: 0-127 key, 128-255 sel, 256-383 val).
// One wave per b; 4 waves/block; LDS rows padded to 392 (conflict-free dots).
// ---------------------------------------------------------------------------
__global__ __launch_bounds__(256, 2)
void attn_k(const us16* __restrict__ ksv, us16* __restrict__ other, int e)
{
  __shared__ us16 t[4][8 * 392];
  const int wv = threadIdx.x >> 6, lane = threadIdx.x & 63;
  const long b = (long)blockIdx.x * 4 + wv;
  const us16* src = ksv + b * 3072;
#pragma unroll
  for (int i = 0; i < 6; i++) {
    int c = i * 64 + lane;                 // 384 16B-chunks (8 rows x 48)
    int r = c / 48, cc = c - r * 48;
    *(int4*)&t[wv][r * 392 + cc * 8] = *(const int4*)&src[c * 8];
  }
  __syncthreads();
  const int i = lane >> 3, j = lane & 7;   // lane = i*8 + j
  const us16* selp = &t[wv][i * 392 + 128];
  const us16* keyp = &t[wv][j * 392];
  float acc = 0.f;
#pragma unroll
  for (int d = 0; d < 128; d += 8) {
    u16x8 s8 = *(const u16x8*)&selp[d];
    u16x8 k8 = *(const u16x8*)&keyp[d];
#pragma unroll
    for (int q = 0; q < 8; q++) acc += bf2f(s8[q]) * bf2f(k8[q]);
  }
  acc *= 0.088388347648318447f;            // 1/sqrt(128)
  float mx = acc;
  mx = fmaxf(mx, __shfl_xor(mx, 1)); mx = fmaxf(mx, __shfl_xor(mx, 2)); mx = fmaxf(mx, __shfl_xor(mx, 4));
  float ex = __expf(acc - mx);
  float sm = ex;
  sm += __shfl_xor(sm, 1); sm += __shfl_xor(sm, 2); sm += __shfl_xor(sm, 4);
  float wsm = ex / sm;
  float wj[8];
  const int ibase = lane & 56;
#pragma unroll
  for (int jj = 0; jj < 8; jj++) wj[jj] = __shfl(wsm, ibase + jj);
  const int dbase = (lane & 7) * 16;       // this lane: agent i, dims dbase..dbase+15
  float o[16];
#pragma unroll
  for (int q = 0; q < 16; q++) o[q] = 0.f;
#pragma unroll
  for (int jj = 0; jj < 8; jj++) {
    u16x8 v0 = *(const u16x8*)&t[wv][jj * 392 + 256 + dbase];
    u16x8 v1 = *(const u16x8*)&t[wv][jj * 392 + 256 + dbase + 8];
    float wgt = wj[jj];
#pragma unroll
    for (int q = 0; q < 8; q++) { o[q] += wgt * bf2f(v0[q]); o[8 + q] += wgt * bf2f(v1[q]); }
  }
  u16x8 r0, r1;
#pragma unroll
  for (int q = 0; q < 8; q++) { r0[q] = f2bf(o[q]); r1[q] = f2bf(o[8 + q]); }
  us16* dst = other + ((long)i * 8192 + b) * 512 + e * 128 + dbase;
  *(u16x8*)&dst[0] = r0;
  *(u16x8*)&dst[8] = r1;
}

// q[r] = b2[r>>13] + sum of 8 per-block partials
__global__ void reduce_dot_k(const float* __restrict__ part, const float* __restrict__ b2,
                             float* __restrict__ out)
{
  int r = blockIdx.x * 256 + threadIdx.x;  // 0..65535
  const float4* p = (const float4*)(part + (long)r * 8);
  float4 a = p[0], b = p[1];
  out[r] = b2[r >> 13] + ((a.x + a.y) + (a.z + a.w)) + ((b.x + b.y) + (b.z + b.w));
}

// ---------------------------------------------------------------------------
extern "C" void kernel_launch(void* const* d_in, const int* in_sizes, int n_in,
                              void* d_out, int out_size, void* d_ws, size_t ws_size,
                              hipStream_t stream)
{
  const float* states = (const float*)d_in[0];
  const float* actions= (const float*)d_in[1];
  const float* Ws  = (const float*)d_in[2];
  const float* bs  = (const float*)d_in[3];
  const float* Wsa = (const float*)d_in[4];
  const float* bsa = (const float*)d_in[5];
  const float* Wk  = (const float*)d_in[6];
  const float* Wsel= (const float*)d_in[7];
  const float* Wv  = (const float*)d_in[8];
  const float* bv  = (const float*)d_in[9];
  const float* Wc1 = (const float*)d_in[10];
  const float* bc1 = (const float*)d_in[11];
  const float* Wc2 = (const float*)d_in[12];
  const float* bc2 = (const float*)d_in[13];
  const float* Wv1 = (const float*)d_in[14];
  const float* bv1 = (const float*)d_in[15];
  const float* Wv2 = (const float*)d_in[16];
  const float* bv2 = (const float*)d_in[17];

  char* ws = (char*)d_ws;
  constexpr size_t OFF_WST   = 0;
  constexpr size_t OFF_WSAT  = OFF_WST   + (size_t)8 * 512 * 64 * 2;
  constexpr size_t OFF_WKVST = OFF_WSAT  + (size_t)8 * 512 * 96 * 2;
  constexpr size_t OFF_WC1T  = OFF_WKVST + (size_t)4 * 384 * 512 * 2;
  constexpr size_t OFF_WV1T  = OFF_WC1T  + (size_t)8 * 512 * 1024 * 2;
  constexpr size_t OFF_ENC   = OFF_WV1T  + (size_t)8 * 512 * 1024 * 2;
  constexpr size_t OFF_OTHER = OFF_ENC   + (size_t)8 * 8192 * 512 * 2;
  constexpr size_t OFF_KSV   = OFF_OTHER + (size_t)8 * 8192 * 512 * 2;
  constexpr size_t OFF_PART  = OFF_KSV   + (size_t)8192 * 8 * 384 * 2;
  constexpr size_t NEED      = OFF_PART  + (size_t)65536 * 8 * 4;
  if (ws_size < NEED) return;  // workspace too small -> loud validation failure

  us16* WST   = (us16*)(ws + OFF_WST);
  us16* WSAT  = (us16*)(ws + OFF_WSAT);
  us16* WKVST = (us16*)(ws + OFF_WKVST);
  us16* WC1T  = (us16*)(ws + OFF_WC1T);
  us16* WV1T  = (us16*)(ws + OFF_WV1T);
  us16* ENC   = (us16*)(ws + OFF_ENC);    // sa_enc, later reused for s_enc
  us16* OTHER = (us16*)(ws + OFF_OTHER);
  us16* KSV   = (us16*)(ws + OFF_KSV);    // one head at a time: [b][n][384]
  float* PART = (float*)(ws + OFF_PART);

  dim3 tb(32, 8);
  tconv_k<<<dim3(2, 16, 8),  tb, 0, stream>>>(Ws,  (long)64 * 512,  64,  512, WST,  (long)512 * 64,  0,   64,   64);
  tconv_k<<<dim3(3, 16, 8),  tb, 0, stream>>>(Wsa, (long)80 * 512,  80,  512, WSAT, (long)512 * 96,  0,   96,   96);
  tconv_k<<<dim3(16, 4, 4),  tb, 0, stream>>>(Wk,  (long)512 * 128, 512, 128, WKVST,(long)384 * 512, 0,   512,  512);
  tconv_k<<<dim3(16, 4, 4),  tb, 0, stream>>>(Wsel,(long)512 * 128, 512, 128, WKVST,(long)384 * 512, 128, 512,  512);
  tconv_k<<<dim3(16, 4, 4),  tb, 0, stream>>>(Wv,  (long)512 * 128, 512, 128, WKVST,(long)384 * 512, 256, 512,  512);
  tconv_k<<<dim3(32, 16, 8), tb, 0, stream>>>(Wc1, (long)1024 * 512,1024,512, WC1T, (long)512 * 1024,0,   1024, 1024);
  tconv_k<<<dim3(32, 16, 8), tb, 0, stream>>>(Wv1, (long)1024 * 512,1024,512, WV1T, (long)512 * 1024,0,   1024, 1024);

  // sa_enc = lrelu([states|actions] @ Wsa + bsa)  -> ENC (bf16)
  enc_gemm_k<ASRC_F32_CAT, 96><<<dim3(64, 4, 8), 256, 0, stream>>>(
      states, (long)8192 * 64, actions, (long)8192 * 16, WSAT, (long)512 * 96, bsa, 512,
      ENC, (long)8192 * 512, 512);

  // per head: ksv = sa_enc @ [Wk|Wsel|Wv] (+bv,lrelu on vals), then attention
  for (int e = 0; e < 4; e++) {
    gemm64_k<false, EPI_KSV, 512><<<dim3(64, 3, 8), 256, 0, stream>>>(
        ENC, (long)8192 * 512, nullptr, 0, WKVST + (size_t)e * 384 * 512, 0, bv + e * 128,
        KSV, 384, 3072, nullptr, nullptr);
    attn_k<<<dim3(2048), 256, 0, stream>>>(KSV, OTHER, e);
  }

  // q = lrelu([sa_enc|other] @ Wc1 + bc1) @ Wc2 + bc2
  gemm64_k<true, EPI_DOT, 1024><<<dim3(64, 4, 8), 256, 0, stream>>>(
      ENC, (long)8192 * 512, OTHER, (long)8192 * 512, WC1T, (long)512 * 1024, bc1,
      nullptr, 0, 0, Wc2, PART);
  reduce_dot_k<<<dim3(256), 256, 0, stream>>>(PART, bc2, (float*)d_out);

  // s_enc = lrelu(states @ Ws + bs) -> ENC (sa_enc is dead now)
  enc_gemm_k<ASRC_F32, 64><<<dim3(64, 4, 8), 256, 0, stream>>>(
      states, (long)8192 * 64, nullptr, 0, WST, (long)512 * 64, bs, 512,
      ENC, (long)8192 * 512, 512);

  // v = lrelu([s_enc|other] @ Wv1 + bv1) @ Wv2 + bv2
  gemm64_k<true, EPI_DOT, 1024><<<dim3(64, 4, 8), 256, 0, stream>>>(
      ENC, (long)8192 * 512, OTHER, (long)8192 * 512, WV1T, (long)512 * 1024, bv1,
      nullptr, 0, 0, Wv2, PART);
  reduce_dot_k<<<dim3(256), 256, 0, stream>>>(PART, bv2, (float*)d_out + 65536);
}